// Round 1
// baseline (140.327 us; speedup 1.0000x reference)
//
#include <hip/hip_runtime.h>
#include <stdint.h>
#include <stddef.h>

// Problem constants (fixed by the reference): B=16, H=8, N=256, D=32
constexpr int Bc = 16;
constexpr int Hc = 8;
constexpr int Nc = 256;
constexpr int Dc = 32;
constexpr float LOG2E = 1.44269504088896340736f;

// silu(x) = x * sigmoid(x) = x / (1 + exp(-x))
__device__ __forceinline__ float silu_fast(float x) {
    float e = __builtin_amdgcn_exp2f(-x * LOG2E);      // exp(-x)
    float r = __builtin_amdgcn_rcpf(1.0f + e);         // 1/(1+exp(-x))
    return x * r;
}

// Block = 256 threads = 4 waves. Each wave handles one query row i of one
// (b,h). k tile (256x32 fp32 = 32 KB) staged in LDS once per block with an
// XOR swizzle on the float4-chunk index so that strided per-lane row reads
// are bank-conflict free (each 8-lane octet covers all 32 banks).
__global__ __launch_bounds__(256) void gatv2_attn_kernel(
    const float*  __restrict__ q,      // [B,H,N,D]
    const float*  __restrict__ k,      // [B,H,N,D]
    const uint8_t* __restrict__ mask,  // [B,1,N,N] bool (1 byte each)
    const float*  __restrict__ att,    // [1,H,1,1,D]
    float*        __restrict__ out)    // [B,H,N,N]
{
    __shared__ float4 kt[Nc * (Dc / 4)];   // 2048 float4 = 32 KB, swizzled

    const int tid  = threadIdx.x;
    const int lane = tid & 63;
    const int wave = tid >> 6;
    const int bh   = blockIdx.y;           // b*H + h
    const int h    = bh & (Hc - 1);
    const int b    = bh >> 3;              // H = 8
    const int i    = blockIdx.x * 4 + wave;

    // ---- stage k tile into LDS (coalesced global read, swizzled write) ----
    const float4* kg = (const float4*)(k + (size_t)bh * Nc * Dc);
#pragma unroll
    for (int it = 0; it < 8; ++it) {
        int flat = it * 256 + tid;         // 0..2047
        int j    = flat >> 3;              // k row
        int c    = flat & 7;               // float4 chunk within row
        kt[(j << 3) | (c ^ (j & 7))] = kg[flat];
    }

    // ---- wave-uniform q row and attention vector (scalarizes to s_load) ----
    const float* qrow = q   + ((size_t)bh * Nc + i) * Dc;
    const float* arow = att + (size_t)h * Dc;
    float qv[Dc], av[Dc];
#pragma unroll
    for (int d = 0; d < Dc; ++d) { qv[d] = qrow[d]; av[d] = arow[d]; }

    const uint8_t* mrow = mask + ((size_t)b * Nc + i) * Nc;

    __syncthreads();

    // ---- scores: lane handles j = lane + 64*t, t = 0..3 ----
    float s[4];
#pragma unroll
    for (int t = 0; t < 4; ++t) {
        const int j  = lane + 64 * t;
        const int sw = j & 7;
        const int jb = j << 3;
        float acc = 0.0f;
#pragma unroll
        for (int c = 0; c < 8; ++c) {
            float4 kv = kt[jb | (c ^ sw)];   // true chunk c of k row j
            const int d = c * 4;
            acc += av[d + 0] * silu_fast(qv[d + 0] + kv.x);
            acc += av[d + 1] * silu_fast(qv[d + 1] + kv.y);
            acc += av[d + 2] * silu_fast(qv[d + 2] + kv.z);
            acc += av[d + 3] * silu_fast(qv[d + 3] + kv.w);
        }
        // True == masked out -> very negative (matches jnp.finfo.min semantics)
        s[t] = mrow[j] ? -3.0e38f : acc;
    }

    // ---- softmax over j (256 values: 4/lane x 64 lanes) ----
    float m = s[0];
    m = fmaxf(m, s[1]); m = fmaxf(m, s[2]); m = fmaxf(m, s[3]);
#pragma unroll
    for (int off = 32; off >= 1; off >>= 1)
        m = fmaxf(m, __shfl_xor(m, off, 64));

    float p[4];
    float sum = 0.0f;
#pragma unroll
    for (int t = 0; t < 4; ++t) {
        p[t] = __builtin_amdgcn_exp2f((s[t] - m) * LOG2E);
        sum += p[t];
    }
#pragma unroll
    for (int off = 32; off >= 1; off >>= 1)
        sum += __shfl_xor(sum, off, 64);

    const float inv = __builtin_amdgcn_rcpf(sum);

    float* orow = out + ((size_t)bh * Nc + i) * Nc;
#pragma unroll
    for (int t = 0; t < 4; ++t)
        orow[lane + 64 * t] = p[t] * inv;   // coalesced 256B stores
}

extern "C" void kernel_launch(void* const* d_in, const int* in_sizes, int n_in,
                              void* d_out, int out_size, void* d_ws, size_t ws_size,
                              hipStream_t stream) {
    const float*   q    = (const float*)d_in[0];
    const float*   k    = (const float*)d_in[1];
    // d_in[2] = scale (unused by the module)
    const uint8_t* mask = (const uint8_t*)d_in[3];
    const float*   att  = (const float*)d_in[4];
    float*         out  = (float*)d_out;

    dim3 grid(Nc / 4, Bc * Hc);   // 64 x 128 blocks, 4 query rows per block
    dim3 block(256);
    gatv2_attn_kernel<<<grid, block, 0, stream>>>(q, k, mask, att, out);
}